// Round 3
// baseline (2784.135 us; speedup 1.0000x reference)
//
#include <hip/hip_runtime.h>

#define N_NODESC 100000
#define N_EDGESC 600000
#define E_TOTC   700000
#define NUM_GRAPHSC 512
#define NEG_SLOPE 0.2f
#define NEG_INF_ENC 0x007FFFFFu
#define SCAN_NB 128

// monotone float<->uint mapping so unsigned atomicMax == float max
__device__ __forceinline__ unsigned enc_f32(float f) {
    unsigned u = __float_as_uint(f);
    return (u & 0x80000000u) ? ~u : (u | 0x80000000u);
}
__device__ __forceinline__ float dec_f32(unsigned u) {
    u = (u & 0x80000000u) ? (u ^ 0x80000000u) : ~u;
    return __uint_as_float(u);
}

__global__ void fill_u32(unsigned* __restrict__ p, unsigned v, int n) {
    int i = blockIdx.x * blockDim.x + threadIdx.x;
    if (i < n) p[i] = v;
}

// ---------------- CSR build ----------------
__global__ __launch_bounds__(256) void hist_dst(const int* __restrict__ ei,
                                                int* __restrict__ deg) {
    int e = blockIdx.x * blockDim.x + threadIdx.x;
    if (e < N_EDGESC) atomicAdd(&deg[ei[N_EDGESC + e]], 1);
}

// phase A: per-block partial sums (SCAN_NB blocks x 256 thr)
__global__ __launch_bounds__(256) void scan_partial(const int* __restrict__ deg,
                                                    int* __restrict__ bsum, int n) {
    __shared__ int red[256];
    int chunk = (n + SCAN_NB - 1) / SCAN_NB;
    int lo = blockIdx.x * chunk, hi = min(lo + chunk, n);
    int s = 0;
    for (int i = lo + threadIdx.x; i < hi; i += 256) s += deg[i];
    red[threadIdx.x] = s;
    __syncthreads();
    for (int d = 128; d; d >>= 1) {
        if (threadIdx.x < d) red[threadIdx.x] += red[threadIdx.x + d];
        __syncthreads();
    }
    if (threadIdx.x == 0) bsum[blockIdx.x] = red[0];
}

// phase B: exclusive scan of the SCAN_NB partials (1 block)
__global__ __launch_bounds__(SCAN_NB) void scan_bsum(int* __restrict__ bsum) {
    __shared__ int tmp[SCAN_NB];
    int t = threadIdx.x;
    tmp[t] = bsum[t];
    __syncthreads();
    for (int d = 1; d < SCAN_NB; d <<= 1) {
        int v = (t >= d) ? tmp[t - d] : 0;
        __syncthreads();
        tmp[t] += v;
        __syncthreads();
    }
    bsum[t] = t ? tmp[t - 1] : 0;
}

// phase C: block-local exclusive scan + carry
__global__ __launch_bounds__(256) void scan_final(const int* __restrict__ deg,
                                                  const int* __restrict__ bsum,
                                                  int* __restrict__ off, int n) {
    __shared__ int tile[256];
    __shared__ int carry;
    int chunk = (n + SCAN_NB - 1) / SCAN_NB;
    int lo = blockIdx.x * chunk, hi = min(lo + chunk, n);
    if (threadIdx.x == 0) carry = bsum[blockIdx.x];
    __syncthreads();
    for (int base = lo; base < hi; base += 256) {
        int i = base + threadIdx.x;
        int v = (i < hi) ? deg[i] : 0;
        tile[threadIdx.x] = v;
        __syncthreads();
        for (int d = 1; d < 256; d <<= 1) {
            int u = (threadIdx.x >= d) ? tile[threadIdx.x - d] : 0;
            __syncthreads();
            tile[threadIdx.x] += u;
            __syncthreads();
        }
        if (i < hi) off[i] = carry + tile[threadIdx.x] - v;
        __syncthreads();
        if (threadIdx.x == 0) carry += tile[255];
        __syncthreads();
    }
}

// scatter src ids into CSR slots; off[d] advances from start to end
__global__ __launch_bounds__(256) void scatter_csr(const int* __restrict__ ei,
                                                   int* __restrict__ off,
                                                   int* __restrict__ csr) {
    int e = blockIdx.x * blockDim.x + threadIdx.x;
    if (e >= E_TOTC) return;
    int s, d;
    if (e < N_EDGESC) { s = ei[e]; d = ei[N_EDGESC + e]; } else { s = d = e - N_EDGESC; }
    int slot = atomicAdd(&off[d], 1);
    csr[slot] = s;
}

// ---------------- GEMM with fused attention-logit epilogue ----------------
// Y[n,j] = sum_k X[n,k]*W[k,j]; K=128. blockDim=(FOUT, 256/FOUT).
// Each wave spans exactly one head's 64 columns -> shfl-reduce alpha in epilogue.
template <int FOUT, int NPT, int H>
__global__ __launch_bounds__(256) void gemm_alpha(const float* __restrict__ X,
                                                  const float* __restrict__ W,
                                                  const float* __restrict__ a_s,
                                                  const float* __restrict__ a_d,
                                                  float* __restrict__ Y,
                                                  float* __restrict__ as_out,
                                                  float* __restrict__ ad_out, int N) {
    constexpr int K = 128;
    constexpr int NROWS = 256 / FOUT;
    constexpr int NPB = NROWS * NPT;
    __shared__ float xs[NPB][K];
    int tid = threadIdx.y * FOUT + threadIdx.x;
    size_t node0 = (size_t)blockIdx.x * NPB;
    const float4* Xv = (const float4*)(X + node0 * K);
    float4* xsv = (float4*)(&xs[0][0]);
#pragma unroll
    for (int i = 0; i < NPB * K / 4 / 256; ++i) xsv[tid + i * 256] = Xv[tid + i * 256];
    __syncthreads();
    int j = threadIdx.x;
    float sa = a_s[j], da = a_d[j];
    float acc[NPT];
#pragma unroll
    for (int r = 0; r < NPT; ++r) acc[r] = 0.f;
    const float* xrow = &xs[threadIdx.y * NPT][0];
#pragma unroll
    for (int k = 0; k < K; ++k) {
        float w = W[k * FOUT + j];
#pragma unroll
        for (int r = 0; r < NPT; ++r) acc[r] += xrow[r * K + k] * w;
    }
    int head = j >> 6;
#pragma unroll
    for (int r = 0; r < NPT; ++r) {
        size_t node = node0 + threadIdx.y * NPT + r;
        Y[node * FOUT + j] = acc[r];
        float ps = acc[r] * sa, pd = acc[r] * da;
#pragma unroll
        for (int sh = 32; sh; sh >>= 1) {
            ps += __shfl_xor(ps, sh);
            pd += __shfl_xor(pd, sh);
        }
        if ((j & 63) == 0) {
            as_out[node * H + head] = ps;
            ad_out[node * H + head] = pd;
        }
    }
}

// ---------------- fused gather aggregation, single-pass online softmax ------
template <int H, bool RELU>
__global__ __launch_bounds__(256) void gat_gather(const int* __restrict__ off_end,
                                                  const int* __restrict__ deg,
                                                  const int* __restrict__ csr,
                                                  const float* __restrict__ as,
                                                  const float* __restrict__ ad,
                                                  const float* __restrict__ Hbuf,
                                                  const float* __restrict__ b,
                                                  float* __restrict__ out, int N) {
    constexpr int HC = H * 64;
    int wid = threadIdx.x >> 6, lane = threadIdx.x & 63;
    int n = blockIdx.x * 4 + wid;
    if (n >= N) return;
    int dg = deg[n];
    int o = off_end[n] - dg;
    float adv[H];
#pragma unroll
    for (int h = 0; h < H; ++h) adv[h] = ad[n * H + h];

    float mx[H], acc[H], den[H];
#pragma unroll
    for (int h = 0; h < H; ++h) { mx[h] = -1e30f; acc[h] = 0.f; den[h] = 0.f; }

    for (int base = 0; base < dg; base += 64) {
        int i = base + lane;
        bool valid = i < dg;
        int s = valid ? csr[o + i] : 0;
        float v[H];
        if (H == 2) {
            float2 p = valid ? ((const float2*)as)[s] : make_float2(-1e30f, -1e30f);
            v[0] = p.x + adv[0];
            v[H - 1] = p.y + adv[H - 1];
        } else {
            v[0] = valid ? as[s] + adv[0] : -1e30f;
        }
#pragma unroll
        for (int h = 0; h < H; ++h) {
            if (valid) v[h] = v[h] >= 0.f ? v[h] : NEG_SLOPE * v[h];
            float cm = v[h];
#pragma unroll
            for (int sh = 32; sh; sh >>= 1) cm = fmaxf(cm, __shfl_xor(cm, sh));
            float nm = fmaxf(mx[h], cm);
            float scale = __expf(mx[h] - nm);  // mx=-1e30 first pass -> 0 (or 1 if nm also -1e30; acc=den=0 then)
            den[h] *= scale;
            acc[h] *= scale;
            mx[h] = nm;
            v[h] = valid ? __expf(v[h] - nm) : 0.f;  // v now holds weight
            den[h] += v[h];
        }
        int cnt = min(dg - base, 64);
        for (int j = 0; j < cnt; ++j) {
            int sj = __shfl(s, j);
#pragma unroll
            for (int h = 0; h < H; ++h) {
                float wj = __shfl(v[h], j);
                acc[h] += wj * Hbuf[(size_t)sj * HC + h * 64 + lane];
            }
        }
    }
#pragma unroll
    for (int h = 0; h < H; ++h) {
#pragma unroll
        for (int sh = 32; sh; sh >>= 1) den[h] += __shfl_xor(den[h], sh);
        float v = acc[h] / fmaxf(den[h], 1e-16f) + b[h * 64 + lane];
        if (RELU) v = fmaxf(v, 0.f);
        out[(size_t)n * HC + h * 64 + lane] = v;
    }
}

// ---------------- pooling: batch is SORTED -> segment-local reduce ----------
// one wave per 64-node contiguous strip; flush atomics only on graph change
__global__ __launch_bounds__(256) void pool_nodes(const float* __restrict__ h2,
                                                  const int* __restrict__ batch,
                                                  float* __restrict__ msum,
                                                  unsigned* __restrict__ mmax,
                                                  float* __restrict__ cnt, int N) {
    int wid = threadIdx.x >> 6, lane = threadIdx.x & 63;
    int n0 = (blockIdx.x * 4 + wid) * 64;
    if (n0 >= N) return;
    int n1 = min(n0 + 64, N);
    int curg = batch[n0];
    float s = 0.f, m = -1e30f;
    int c = 0;
    for (int n = n0; n < n1; ++n) {
        int g = batch[n];
        float v = h2[(size_t)n * 64 + lane];
        if (g != curg) {
            atomicAdd(&msum[curg * 64 + lane], s);
            atomicMax(&mmax[curg * 64 + lane], enc_f32(m));
            if (lane == 0) atomicAdd(&cnt[curg], (float)c);
            s = 0.f; m = -1e30f; c = 0; curg = g;
        }
        s += v;
        m = fmaxf(m, v);
        ++c;
    }
    atomicAdd(&msum[curg * 64 + lane], s);
    atomicMax(&mmax[curg * 64 + lane], enc_f32(m));
    if (lane == 0) atomicAdd(&cnt[curg], (float)c);
}

__global__ __launch_bounds__(64) void mlp_head(const float* __restrict__ msum,
                                               const unsigned* __restrict__ mmax,
                                               const float* __restrict__ cnt,
                                               const float* __restrict__ Wf1,
                                               const float* __restrict__ bf1,
                                               const float* __restrict__ Wf2,
                                               const float* __restrict__ bf2,
                                               float* __restrict__ out) {
    __shared__ float pooled[128];
    int g = blockIdx.x, lane = threadIdx.x;
    float c = cnt[g];
    pooled[lane] = msum[g * 64 + lane] / fmaxf(c, 1.0f);
    pooled[64 + lane] = (c > 0.f) ? dec_f32(mmax[g * 64 + lane]) : 0.f;
    __syncthreads();
    float acc = bf1[lane];
#pragma unroll
    for (int k = 0; k < 128; ++k) acc += pooled[k] * Wf1[k * 64 + lane];
    acc = fmaxf(acc, 0.f);
    float r = acc * Wf2[lane];
#pragma unroll
    for (int off = 32; off; off >>= 1) r += __shfl_xor(r, off);
    if (lane == 0) out[g] = r + bf2[0];
}

extern "C" void kernel_launch(void* const* d_in, const int* in_sizes, int n_in,
                              void* d_out, int out_size, void* d_ws, size_t ws_size,
                              hipStream_t stream) {
    const float* x    = (const float*)d_in[0];
    const int*   ei   = (const int*)d_in[1];
    const int*   batch= (const int*)d_in[2];
    const float* W1   = (const float*)d_in[3];
    const float* as1  = (const float*)d_in[4];
    const float* ad1  = (const float*)d_in[5];
    const float* b1   = (const float*)d_in[6];
    const float* W2   = (const float*)d_in[7];
    const float* as2  = (const float*)d_in[8];
    const float* ad2  = (const float*)d_in[9];
    const float* b2   = (const float*)d_in[10];
    const float* Wf1  = (const float*)d_in[11];
    const float* bf1  = (const float*)d_in[12];
    const float* Wf2  = (const float*)d_in[13];
    const float* bf2  = (const float*)d_in[14];
    float* out = (float*)d_out;

    const size_t N = N_NODESC;
    float* ws = (float*)d_ws;
    float* h1   = ws;            // [N,128] layer1; layer2: h2=[0,N*64), out2=[N*64,N*128)
    float* out1 = ws + N * 128;  // [N,128] layer1 output (layer2 GEMM input)
    float* small = ws + 2 * N * 128;
    float*    as1b = small;                    // 2N
    float*    ad1b = small + 2 * N;            // 2N
    float*    as2b = small + 4 * N;            // N
    float*    ad2b = small + 5 * N;            // N
    float*    msum = small + 6 * N;            // 512*64
    unsigned* mmax = (unsigned*)(small + 6 * N + 512 * 64);
    float*    cntb = small + 6 * N + 2 * 512 * 64;  // 512
    int* ip  = (int*)(small + 6 * N + 2 * 512 * 64 + 512);
    int* deg  = ip;              // N
    int* off  = ip + N;          // N (start offsets; scatter advances to end)
    int* csr  = ip + 2 * N;      // E_TOT src ids
    int* bsum = ip + 2 * N + E_TOTC;  // SCAN_NB
    float* h2   = h1;
    float* out2 = h1 + N * 64;

    // init
    hipMemsetAsync(msum, 0, 512 * 64 * 4, stream);
    hipMemsetAsync(cntb, 0, 512 * 4, stream);
    fill_u32<<<(512 * 64 + 255) / 256, 256, 0, stream>>>(mmax, NEG_INF_ENC, 512 * 64);
    fill_u32<<<(N + 255) / 256, 256, 0, stream>>>((unsigned*)deg, 1u, N);  // self-loop

    // CSR build (reused by both layers)
    hist_dst<<<(N_EDGESC + 255) / 256, 256, 0, stream>>>(ei, deg);
    scan_partial<<<SCAN_NB, 256, 0, stream>>>(deg, bsum, N);
    scan_bsum<<<1, SCAN_NB, 0, stream>>>(bsum);
    scan_final<<<SCAN_NB, 256, 0, stream>>>(deg, bsum, off, N);
    scatter_csr<<<(E_TOTC + 255) / 256, 256, 0, stream>>>(ei, off, csr);

    // ---- layer 1 (H=2) ----
    gemm_alpha<128, 8, 2><<<N / 16, dim3(128, 2), 0, stream>>>(x, W1, as1, ad1,
                                                               h1, as1b, ad1b, N);
    gat_gather<2, true><<<(N + 3) / 4, 256, 0, stream>>>(off, deg, csr, as1b, ad1b,
                                                         h1, b1, out1, N);

    // ---- layer 2 (H=1) ----
    gemm_alpha<64, 8, 1><<<N / 32, dim3(64, 4), 0, stream>>>(out1, W2, as2, ad2,
                                                             h2, as2b, ad2b, N);
    gat_gather<1, false><<<(N + 3) / 4, 256, 0, stream>>>(off, deg, csr, as2b, ad2b,
                                                          h2, b2, out2, N);

    // ---- pool + MLP ----
    pool_nodes<<<(N + 255) / 256, 256, 0, stream>>>(out2, batch, msum, mmax, cntb, N);
    mlp_head<<<NUM_GRAPHSC, 64, 0, stream>>>(msum, mmax, cntb, Wf1, bf1, Wf2, bf2, out);
}

// Round 4
// 478.431 us; speedup vs baseline: 5.8193x; 5.8193x over previous
//
#include <hip/hip_runtime.h>

#define N_NODESC 100000
#define N_EDGESC 600000
#define E_TOTC   700000
#define NUM_GRAPHSC 512
#define NEG_SLOPE 0.2f
#define NEG_INF_ENC 0x007FFFFFu
#define SCAN_NB 128

// monotone float<->uint mapping so unsigned atomicMax == float max
__device__ __forceinline__ unsigned enc_f32(float f) {
    unsigned u = __float_as_uint(f);
    return (u & 0x80000000u) ? ~u : (u | 0x80000000u);
}
__device__ __forceinline__ float dec_f32(unsigned u) {
    u = (u & 0x80000000u) ? (u ^ 0x80000000u) : ~u;
    return __uint_as_float(u);
}

__global__ void fill_u32(unsigned* __restrict__ p, unsigned v, int n) {
    int i = blockIdx.x * blockDim.x + threadIdx.x;
    if (i < n) p[i] = v;
}

// ---------------- CSR build ----------------
__global__ __launch_bounds__(256) void hist_dst(const int* __restrict__ ei,
                                                int* __restrict__ deg) {
    int e = blockIdx.x * blockDim.x + threadIdx.x;
    if (e < N_EDGESC) atomicAdd(&deg[ei[N_EDGESC + e]], 1);
}

// phase A: per-block partial sums (SCAN_NB blocks x 256 thr)
__global__ __launch_bounds__(256) void scan_partial(const int* __restrict__ deg,
                                                    int* __restrict__ bsum, int n) {
    __shared__ int red[256];
    int chunk = (n + SCAN_NB - 1) / SCAN_NB;
    int lo = blockIdx.x * chunk, hi = min(lo + chunk, n);
    int s = 0;
    for (int i = lo + threadIdx.x; i < hi; i += 256) s += deg[i];
    red[threadIdx.x] = s;
    __syncthreads();
    for (int d = 128; d; d >>= 1) {
        if (threadIdx.x < d) red[threadIdx.x] += red[threadIdx.x + d];
        __syncthreads();
    }
    if (threadIdx.x == 0) bsum[blockIdx.x] = red[0];
}

// phase B: exclusive scan of the SCAN_NB partials (1 block)
__global__ __launch_bounds__(SCAN_NB) void scan_bsum(int* __restrict__ bsum) {
    __shared__ int tmp[SCAN_NB];
    int t = threadIdx.x;
    tmp[t] = bsum[t];
    __syncthreads();
    for (int d = 1; d < SCAN_NB; d <<= 1) {
        int v = (t >= d) ? tmp[t - d] : 0;
        __syncthreads();
        tmp[t] += v;
        __syncthreads();
    }
    bsum[t] = t ? tmp[t - 1] : 0;
}

// phase C: block-local exclusive scan + carry
__global__ __launch_bounds__(256) void scan_final(const int* __restrict__ deg,
                                                  const int* __restrict__ bsum,
                                                  int* __restrict__ off, int n) {
    __shared__ int tile[256];
    __shared__ int carry;
    int chunk = (n + SCAN_NB - 1) / SCAN_NB;
    int lo = blockIdx.x * chunk, hi = min(lo + chunk, n);
    if (threadIdx.x == 0) carry = bsum[blockIdx.x];
    __syncthreads();
    for (int base = lo; base < hi; base += 256) {
        int i = base + threadIdx.x;
        int v = (i < hi) ? deg[i] : 0;
        tile[threadIdx.x] = v;
        __syncthreads();
        for (int d = 1; d < 256; d <<= 1) {
            int u = (threadIdx.x >= d) ? tile[threadIdx.x - d] : 0;
            __syncthreads();
            tile[threadIdx.x] += u;
            __syncthreads();
        }
        if (i < hi) off[i] = carry + tile[threadIdx.x] - v;
        __syncthreads();
        if (threadIdx.x == 0) carry += tile[255];
        __syncthreads();
    }
}

// scatter src ids into CSR slots; off[d] advances from start to end
__global__ __launch_bounds__(256) void scatter_csr(const int* __restrict__ ei,
                                                   int* __restrict__ off,
                                                   int* __restrict__ csr) {
    int e = blockIdx.x * blockDim.x + threadIdx.x;
    if (e >= E_TOTC) return;
    int s, d;
    if (e < N_EDGESC) { s = ei[e]; d = ei[N_EDGESC + e]; } else { s = d = e - N_EDGESC; }
    int slot = atomicAdd(&off[d], 1);
    csr[slot] = s;
}

// ---------------- dense GEMM (R2-proven register profile; do NOT fuse
// cross-lane reductions into this body — R3 showed it spills to scratch) ----
// Y[n,j] = sum_k X[n,k] * W[k,j];  K = 128 fixed. blockDim=(FOUT, 256/FOUT)
template <int FOUT, int NPT>
__global__ __launch_bounds__(256) void gemm_rm(const float* __restrict__ X,
                                               const float* __restrict__ W,
                                               float* __restrict__ Y, int N) {
    constexpr int K = 128;
    constexpr int NROWS = 256 / FOUT;
    constexpr int NPB = NROWS * NPT;
    __shared__ float xs[NPB][K];
    int tid = threadIdx.y * FOUT + threadIdx.x;
    size_t node0 = (size_t)blockIdx.x * NPB;
    const float4* Xv = (const float4*)(X + node0 * K);
    float4* xsv = (float4*)(&xs[0][0]);
#pragma unroll
    for (int i = 0; i < NPB * K / 4 / 256; ++i) xsv[tid + i * 256] = Xv[tid + i * 256];
    __syncthreads();
    int j = threadIdx.x;
    float acc[NPT];
#pragma unroll
    for (int r = 0; r < NPT; ++r) acc[r] = 0.f;
    const float* xrow = &xs[threadIdx.y * NPT][0];
#pragma unroll
    for (int k = 0; k < K; ++k) {
        float w = W[k * FOUT + j];
#pragma unroll
        for (int r = 0; r < NPT; ++r) acc[r] += xrow[r * K + k] * w;
    }
#pragma unroll
    for (int r = 0; r < NPT; ++r)
        Y[(node0 + threadIdx.y * NPT + r) * FOUT + j] = acc[r];
}

// per-node attention logits: one wave per node, C=64 lanes
template <int H>
__global__ __launch_bounds__(256) void node_alpha(const float* __restrict__ Hbuf,
                                                  const float* __restrict__ a_s,
                                                  const float* __restrict__ a_d,
                                                  float* __restrict__ as_out,
                                                  float* __restrict__ ad_out, int N) {
    int wid = threadIdx.x >> 6, lane = threadIdx.x & 63;
    int n = blockIdx.x * 4 + wid;
    if (n >= N) return;
    const float* hrow = Hbuf + (size_t)n * (H * 64);
#pragma unroll
    for (int h = 0; h < H; ++h) {
        float hv = hrow[h * 64 + lane];
        float ps = hv * a_s[h * 64 + lane];
        float pd = hv * a_d[h * 64 + lane];
#pragma unroll
        for (int off = 32; off; off >>= 1) {
            ps += __shfl_xor(ps, off);
            pd += __shfl_xor(pd, off);
        }
        if (lane == 0) { as_out[n * H + h] = ps; ad_out[n * H + h] = pd; }
    }
}

// ---------------- fused gather aggregation, single-pass online softmax ------
template <int H, bool RELU>
__global__ __launch_bounds__(256) void gat_gather(const int* __restrict__ off_end,
                                                  const int* __restrict__ deg,
                                                  const int* __restrict__ csr,
                                                  const float* __restrict__ as,
                                                  const float* __restrict__ ad,
                                                  const float* __restrict__ Hbuf,
                                                  const float* __restrict__ b,
                                                  float* __restrict__ out, int N) {
    constexpr int HC = H * 64;
    int wid = threadIdx.x >> 6, lane = threadIdx.x & 63;
    int n = blockIdx.x * 4 + wid;
    if (n >= N) return;
    int dg = deg[n];
    int o = off_end[n] - dg;
    float adv[H];
#pragma unroll
    for (int h = 0; h < H; ++h) adv[h] = ad[n * H + h];

    float mx[H], acc[H], den[H];
#pragma unroll
    for (int h = 0; h < H; ++h) { mx[h] = -1e30f; acc[h] = 0.f; den[h] = 0.f; }

    for (int base = 0; base < dg; base += 64) {
        int i = base + lane;
        bool valid = i < dg;
        int s = valid ? csr[o + i] : 0;
        float v[H];
        if (H == 2) {
            float2 p = valid ? ((const float2*)as)[s] : make_float2(-1e30f, -1e30f);
            v[0] = p.x + adv[0];
            v[H - 1] = p.y + adv[H - 1];
        } else {
            v[0] = valid ? as[s] + adv[0] : -1e30f;
        }
#pragma unroll
        for (int h = 0; h < H; ++h) {
            if (valid) v[h] = v[h] >= 0.f ? v[h] : NEG_SLOPE * v[h];
            float cm = v[h];
#pragma unroll
            for (int sh = 32; sh; sh >>= 1) cm = fmaxf(cm, __shfl_xor(cm, sh));
            float nm = fmaxf(mx[h], cm);
            float scale = __expf(mx[h] - nm);
            den[h] *= scale;
            acc[h] *= scale;
            mx[h] = nm;
            v[h] = valid ? __expf(v[h] - nm) : 0.f;  // v now holds weight
            den[h] += v[h];
        }
        int cnt = min(dg - base, 64);
        for (int j = 0; j < cnt; ++j) {
            int sj = __shfl(s, j);
#pragma unroll
            for (int h = 0; h < H; ++h) {
                float wj = __shfl(v[h], j);
                acc[h] += wj * Hbuf[(size_t)sj * HC + h * 64 + lane];
            }
        }
    }
#pragma unroll
    for (int h = 0; h < H; ++h) {
#pragma unroll
        for (int sh = 32; sh; sh >>= 1) den[h] += __shfl_xor(den[h], sh);
        float v = acc[h] / fmaxf(den[h], 1e-16f) + b[h * 64 + lane];
        if (RELU) v = fmaxf(v, 0.f);
        out[(size_t)n * HC + h * 64 + lane] = v;
    }
}

// ---------------- pooling: batch is SORTED -> segment-local reduce ----------
// one wave per 64-node contiguous strip; flush atomics only on graph change
__global__ __launch_bounds__(256) void pool_nodes(const float* __restrict__ h2,
                                                  const int* __restrict__ batch,
                                                  float* __restrict__ msum,
                                                  unsigned* __restrict__ mmax,
                                                  float* __restrict__ cnt, int N) {
    int wid = threadIdx.x >> 6, lane = threadIdx.x & 63;
    int n0 = (blockIdx.x * 4 + wid) * 64;
    if (n0 >= N) return;
    int n1 = min(n0 + 64, N);
    int curg = batch[n0];
    float s = 0.f, m = -1e30f;
    int c = 0;
    for (int n = n0; n < n1; ++n) {
        int g = batch[n];
        float v = h2[(size_t)n * 64 + lane];
        if (g != curg) {
            atomicAdd(&msum[curg * 64 + lane], s);
            atomicMax(&mmax[curg * 64 + lane], enc_f32(m));
            if (lane == 0) atomicAdd(&cnt[curg], (float)c);
            s = 0.f; m = -1e30f; c = 0; curg = g;
        }
        s += v;
        m = fmaxf(m, v);
        ++c;
    }
    atomicAdd(&msum[curg * 64 + lane], s);
    atomicMax(&mmax[curg * 64 + lane], enc_f32(m));
    if (lane == 0) atomicAdd(&cnt[curg], (float)c);
}

__global__ __launch_bounds__(64) void mlp_head(const float* __restrict__ msum,
                                               const unsigned* __restrict__ mmax,
                                               const float* __restrict__ cnt,
                                               const float* __restrict__ Wf1,
                                               const float* __restrict__ bf1,
                                               const float* __restrict__ Wf2,
                                               const float* __restrict__ bf2,
                                               float* __restrict__ out) {
    __shared__ float pooled[128];
    int g = blockIdx.x, lane = threadIdx.x;
    float c = cnt[g];
    pooled[lane] = msum[g * 64 + lane] / fmaxf(c, 1.0f);
    pooled[64 + lane] = (c > 0.f) ? dec_f32(mmax[g * 64 + lane]) : 0.f;
    __syncthreads();
    float acc = bf1[lane];
#pragma unroll
    for (int k = 0; k < 128; ++k) acc += pooled[k] * Wf1[k * 64 + lane];
    acc = fmaxf(acc, 0.f);
    float r = acc * Wf2[lane];
#pragma unroll
    for (int off = 32; off; off >>= 1) r += __shfl_xor(r, off);
    if (lane == 0) out[g] = r + bf2[0];
}

extern "C" void kernel_launch(void* const* d_in, const int* in_sizes, int n_in,
                              void* d_out, int out_size, void* d_ws, size_t ws_size,
                              hipStream_t stream) {
    const float* x    = (const float*)d_in[0];
    const int*   ei   = (const int*)d_in[1];
    const int*   batch= (const int*)d_in[2];
    const float* W1   = (const float*)d_in[3];
    const float* as1  = (const float*)d_in[4];
    const float* ad1  = (const float*)d_in[5];
    const float* b1   = (const float*)d_in[6];
    const float* W2   = (const float*)d_in[7];
    const float* as2  = (const float*)d_in[8];
    const float* ad2  = (const float*)d_in[9];
    const float* b2   = (const float*)d_in[10];
    const float* Wf1  = (const float*)d_in[11];
    const float* bf1  = (const float*)d_in[12];
    const float* Wf2  = (const float*)d_in[13];
    const float* bf2  = (const float*)d_in[14];
    float* out = (float*)d_out;

    const size_t N = N_NODESC;
    float* ws = (float*)d_ws;
    float* h1   = ws;            // [N,128] layer1; layer2: h2=[0,N*64), out2=[N*64,N*128)
    float* out1 = ws + N * 128;  // [N,128] layer1 output (layer2 GEMM input)
    float* small = ws + 2 * N * 128;
    float*    as1b = small;                    // 2N
    float*    ad1b = small + 2 * N;            // 2N
    float*    as2b = small + 4 * N;            // N
    float*    ad2b = small + 5 * N;            // N
    float*    msum = small + 6 * N;            // 512*64
    unsigned* mmax = (unsigned*)(small + 6 * N + 512 * 64);
    float*    cntb = small + 6 * N + 2 * 512 * 64;  // 512
    int* ip  = (int*)(small + 6 * N + 2 * 512 * 64 + 512);
    int* deg  = ip;              // N
    int* off  = ip + N;          // N (start offsets; scatter advances to end)
    int* csr  = ip + 2 * N;      // E_TOT src ids
    int* bsum = ip + 2 * N + E_TOTC;  // SCAN_NB
    float* h2   = h1;
    float* out2 = h1 + N * 64;

    // init
    hipMemsetAsync(msum, 0, 512 * 64 * 4, stream);
    hipMemsetAsync(cntb, 0, 512 * 4, stream);
    fill_u32<<<(512 * 64 + 255) / 256, 256, 0, stream>>>(mmax, NEG_INF_ENC, 512 * 64);
    fill_u32<<<(N + 255) / 256, 256, 0, stream>>>((unsigned*)deg, 1u, N);  // self-loop

    // CSR build (reused by both layers)
    hist_dst<<<(N_EDGESC + 255) / 256, 256, 0, stream>>>(ei, deg);
    scan_partial<<<SCAN_NB, 256, 0, stream>>>(deg, bsum, N);
    scan_bsum<<<1, SCAN_NB, 0, stream>>>(bsum);
    scan_final<<<SCAN_NB, 256, 0, stream>>>(deg, bsum, off, N);
    scatter_csr<<<(E_TOTC + 255) / 256, 256, 0, stream>>>(ei, off, csr);

    // ---- layer 1 (H=2) ----
    gemm_rm<128, 8><<<N / 16, dim3(128, 2), 0, stream>>>(x, W1, h1, N);
    node_alpha<2><<<(N + 3) / 4, 256, 0, stream>>>(h1, as1, ad1, as1b, ad1b, N);
    gat_gather<2, true><<<(N + 3) / 4, 256, 0, stream>>>(off, deg, csr, as1b, ad1b,
                                                         h1, b1, out1, N);

    // ---- layer 2 (H=1) ----
    gemm_rm<64, 8><<<N / 32, dim3(64, 4), 0, stream>>>(out1, W2, h2, N);
    node_alpha<1><<<(N + 3) / 4, 256, 0, stream>>>(h2, as2, ad2, as2b, ad2b, N);
    gat_gather<1, false><<<(N + 3) / 4, 256, 0, stream>>>(off, deg, csr, as2b, ad2b,
                                                          h2, b2, out2, N);

    // ---- pool + MLP ----
    pool_nodes<<<(N + 255) / 256, 256, 0, stream>>>(out2, batch, msum, mmax, cntb, N);
    mlp_head<<<NUM_GRAPHSC, 64, 0, stream>>>(msum, mmax, cntb, Wf1, bf1, Wf2, bf2, out);
}

// Round 5
// 470.107 us; speedup vs baseline: 5.9223x; 1.0177x over previous
//
#include <hip/hip_runtime.h>

#define N_NODESC 100000
#define N_EDGESC 600000
#define E_TOTC   700000
#define NUM_GRAPHSC 512
#define NEG_SLOPE 0.2f
#define NEG_INF_ENC 0x007FFFFFu
#define SCAN_NB 128

typedef unsigned short ushort_t;

// monotone float<->uint mapping so unsigned atomicMax == float max
__device__ __forceinline__ unsigned enc_f32(float f) {
    unsigned u = __float_as_uint(f);
    return (u & 0x80000000u) ? ~u : (u | 0x80000000u);
}
__device__ __forceinline__ float dec_f32(unsigned u) {
    u = (u & 0x80000000u) ? (u ^ 0x80000000u) : ~u;
    return __uint_as_float(u);
}
// exact fp32->bf16 RNE (finite values) and bf16->fp32
__device__ __forceinline__ ushort_t f32_to_bf16(float f) {
    unsigned u = __float_as_uint(f);
    return (ushort_t)((u + 0x7FFFu + ((u >> 16) & 1u)) >> 16);
}
__device__ __forceinline__ float bf16_to_f32(ushort_t h) {
    return __uint_as_float(((unsigned)h) << 16);
}

__global__ void fill_u32(unsigned* __restrict__ p, unsigned v, int n) {
    int i = blockIdx.x * blockDim.x + threadIdx.x;
    if (i < n) p[i] = v;
}

// ---------------- CSR build ----------------
__global__ __launch_bounds__(256) void hist_dst(const int* __restrict__ ei,
                                                int* __restrict__ deg) {
    int e = blockIdx.x * blockDim.x + threadIdx.x;
    if (e < N_EDGESC) atomicAdd(&deg[ei[N_EDGESC + e]], 1);
}

__global__ __launch_bounds__(256) void scan_partial(const int* __restrict__ deg,
                                                    int* __restrict__ bsum, int n) {
    __shared__ int red[256];
    int chunk = (n + SCAN_NB - 1) / SCAN_NB;
    int lo = blockIdx.x * chunk, hi = min(lo + chunk, n);
    int s = 0;
    for (int i = lo + threadIdx.x; i < hi; i += 256) s += deg[i];
    red[threadIdx.x] = s;
    __syncthreads();
    for (int d = 128; d; d >>= 1) {
        if (threadIdx.x < d) red[threadIdx.x] += red[threadIdx.x + d];
        __syncthreads();
    }
    if (threadIdx.x == 0) bsum[blockIdx.x] = red[0];
}

__global__ __launch_bounds__(SCAN_NB) void scan_bsum(int* __restrict__ bsum) {
    __shared__ int tmp[SCAN_NB];
    int t = threadIdx.x;
    tmp[t] = bsum[t];
    __syncthreads();
    for (int d = 1; d < SCAN_NB; d <<= 1) {
        int v = (t >= d) ? tmp[t - d] : 0;
        __syncthreads();
        tmp[t] += v;
        __syncthreads();
    }
    bsum[t] = t ? tmp[t - 1] : 0;
}

__global__ __launch_bounds__(256) void scan_final(const int* __restrict__ deg,
                                                  const int* __restrict__ bsum,
                                                  int* __restrict__ off, int n) {
    __shared__ int tile[256];
    __shared__ int carry;
    int chunk = (n + SCAN_NB - 1) / SCAN_NB;
    int lo = blockIdx.x * chunk, hi = min(lo + chunk, n);
    if (threadIdx.x == 0) carry = bsum[blockIdx.x];
    __syncthreads();
    for (int base = lo; base < hi; base += 256) {
        int i = base + threadIdx.x;
        int v = (i < hi) ? deg[i] : 0;
        tile[threadIdx.x] = v;
        __syncthreads();
        for (int d = 1; d < 256; d <<= 1) {
            int u = (threadIdx.x >= d) ? tile[threadIdx.x - d] : 0;
            __syncthreads();
            tile[threadIdx.x] += u;
            __syncthreads();
        }
        if (i < hi) off[i] = carry + tile[threadIdx.x] - v;
        __syncthreads();
        if (threadIdx.x == 0) carry += tile[255];
        __syncthreads();
    }
}

__global__ __launch_bounds__(256) void scatter_csr(const int* __restrict__ ei,
                                                   int* __restrict__ off,
                                                   int* __restrict__ csr) {
    int e = blockIdx.x * blockDim.x + threadIdx.x;
    if (e >= E_TOTC) return;
    int s, d;
    if (e < N_EDGESC) { s = ei[e]; d = ei[N_EDGESC + e]; } else { s = d = e - N_EDGESC; }
    int slot = atomicAdd(&off[d], 1);
    csr[slot] = s;
}

// ---------------- dense GEMM, bf16 output (R2 register profile; no cross-lane
// epilogue fusion — R3 showed that spills to scratch) ------------------------
// Y16[n,j] = bf16( sum_k X[n,k] * W[k,j] );  K = 128. blockDim=(FOUT, 256/FOUT)
template <int FOUT, int NPT>
__global__ __launch_bounds__(256) void gemm_bf16(const float* __restrict__ X,
                                                 const float* __restrict__ W,
                                                 ushort_t* __restrict__ Y16, int N) {
    constexpr int K = 128;
    constexpr int NROWS = 256 / FOUT;
    constexpr int NPB = NROWS * NPT;
    __shared__ float xs[NPB][K];
    int tid = threadIdx.y * FOUT + threadIdx.x;
    size_t node0 = (size_t)blockIdx.x * NPB;
    const float4* Xv = (const float4*)(X + node0 * K);
    float4* xsv = (float4*)(&xs[0][0]);
#pragma unroll
    for (int i = 0; i < NPB * K / 4 / 256; ++i) xsv[tid + i * 256] = Xv[tid + i * 256];
    __syncthreads();
    int j = threadIdx.x;
    float acc[NPT];
#pragma unroll
    for (int r = 0; r < NPT; ++r) acc[r] = 0.f;
    const float* xrow = &xs[threadIdx.y * NPT][0];
#pragma unroll
    for (int k = 0; k < K; ++k) {
        float w = W[k * FOUT + j];
#pragma unroll
        for (int r = 0; r < NPT; ++r) acc[r] += xrow[r * K + k] * w;
    }
#pragma unroll
    for (int r = 0; r < NPT; ++r)
        Y16[(node0 + threadIdx.y * NPT + r) * FOUT + j] = f32_to_bf16(acc[r]);
}

// per-node attention logits from bf16 h: one wave per node
template <int H>
__global__ __launch_bounds__(256) void node_alpha(const ushort_t* __restrict__ H16,
                                                  const float* __restrict__ a_s,
                                                  const float* __restrict__ a_d,
                                                  float* __restrict__ as_out,
                                                  float* __restrict__ ad_out, int N) {
    int wid = threadIdx.x >> 6, lane = threadIdx.x & 63;
    int n = blockIdx.x * 4 + wid;
    if (n >= N) return;
    const ushort_t* hrow = H16 + (size_t)n * (H * 64);
#pragma unroll
    for (int h = 0; h < H; ++h) {
        float hv = bf16_to_f32(hrow[h * 64 + lane]);
        float ps = hv * a_s[h * 64 + lane];
        float pd = hv * a_d[h * 64 + lane];
#pragma unroll
        for (int off = 32; off; off >>= 1) {
            ps += __shfl_xor(ps, off);
            pd += __shfl_xor(pd, off);
        }
        if (lane == 0) { as_out[n * H + h] = ps; ad_out[n * H + h] = pd; }
    }
}

// ---------------- fused gather aggregation, single-pass online softmax ------
template <int H, bool RELU>
__global__ __launch_bounds__(256) void gat_gather(const int* __restrict__ off_end,
                                                  const int* __restrict__ deg,
                                                  const int* __restrict__ csr,
                                                  const float* __restrict__ as,
                                                  const float* __restrict__ ad,
                                                  const ushort_t* __restrict__ H16,
                                                  const float* __restrict__ b,
                                                  float* __restrict__ out, int N) {
    constexpr int HC = H * 64;
    int wid = threadIdx.x >> 6, lane = threadIdx.x & 63;
    int n = blockIdx.x * 4 + wid;
    if (n >= N) return;
    int dg = deg[n];
    int o = off_end[n] - dg;
    float adv[H];
#pragma unroll
    for (int h = 0; h < H; ++h) adv[h] = ad[n * H + h];

    float mx[H], acc[H], den[H];
#pragma unroll
    for (int h = 0; h < H; ++h) { mx[h] = -1e30f; acc[h] = 0.f; den[h] = 0.f; }

    for (int base = 0; base < dg; base += 64) {
        int i = base + lane;
        bool valid = i < dg;
        int s = valid ? csr[o + i] : 0;
        float v[H];
        if (H == 2) {
            float2 p = valid ? ((const float2*)as)[s] : make_float2(-1e30f, -1e30f);
            v[0] = p.x + adv[0];
            v[H - 1] = p.y + adv[H - 1];
        } else {
            v[0] = valid ? as[s] + adv[0] : -1e30f;
        }
#pragma unroll
        for (int h = 0; h < H; ++h) {
            if (valid) v[h] = v[h] >= 0.f ? v[h] : NEG_SLOPE * v[h];
            float cm = v[h];
#pragma unroll
            for (int sh = 32; sh; sh >>= 1) cm = fmaxf(cm, __shfl_xor(cm, sh));
            float nm = fmaxf(mx[h], cm);
            float scale = __expf(mx[h] - nm);
            den[h] *= scale;
            acc[h] *= scale;
            mx[h] = nm;
            v[h] = valid ? __expf(v[h] - nm) : 0.f;  // v now holds weight
            den[h] += v[h];
        }
        int cnt = min(dg - base, 64);
        for (int j = 0; j < cnt; ++j) {
            int sj = __shfl(s, j);
#pragma unroll
            for (int h = 0; h < H; ++h) {
                float wj = __shfl(v[h], j);
                acc[h] += wj * bf16_to_f32(H16[(size_t)sj * HC + h * 64 + lane]);
            }
        }
    }
#pragma unroll
    for (int h = 0; h < H; ++h) {
#pragma unroll
        for (int sh = 32; sh; sh >>= 1) den[h] += __shfl_xor(den[h], sh);
        float v = acc[h] / fmaxf(den[h], 1e-16f) + b[h * 64 + lane];
        if (RELU) v = fmaxf(v, 0.f);
        out[(size_t)n * HC + h * 64 + lane] = v;
    }
}

// ---------------- pooling: batch is SORTED -> segment-local reduce ----------
__global__ __launch_bounds__(256) void pool_nodes(const float* __restrict__ h2,
                                                  const int* __restrict__ batch,
                                                  float* __restrict__ msum,
                                                  unsigned* __restrict__ mmax,
                                                  float* __restrict__ cnt, int N) {
    int wid = threadIdx.x >> 6, lane = threadIdx.x & 63;
    int n0 = (blockIdx.x * 4 + wid) * 64;
    if (n0 >= N) return;
    int n1 = min(n0 + 64, N);
    int curg = batch[n0];
    float s = 0.f, m = -1e30f;
    int c = 0;
    for (int n = n0; n < n1; ++n) {
        int g = batch[n];
        float v = h2[(size_t)n * 64 + lane];
        if (g != curg) {
            atomicAdd(&msum[curg * 64 + lane], s);
            atomicMax(&mmax[curg * 64 + lane], enc_f32(m));
            if (lane == 0) atomicAdd(&cnt[curg], (float)c);
            s = 0.f; m = -1e30f; c = 0; curg = g;
        }
        s += v;
        m = fmaxf(m, v);
        ++c;
    }
    atomicAdd(&msum[curg * 64 + lane], s);
    atomicMax(&mmax[curg * 64 + lane], enc_f32(m));
    if (lane == 0) atomicAdd(&cnt[curg], (float)c);
}

__global__ __launch_bounds__(64) void mlp_head(const float* __restrict__ msum,
                                               const unsigned* __restrict__ mmax,
                                               const float* __restrict__ cnt,
                                               const float* __restrict__ Wf1,
                                               const float* __restrict__ bf1,
                                               const float* __restrict__ Wf2,
                                               const float* __restrict__ bf2,
                                               float* __restrict__ out) {
    __shared__ float pooled[128];
    int g = blockIdx.x, lane = threadIdx.x;
    float c = cnt[g];
    pooled[lane] = msum[g * 64 + lane] / fmaxf(c, 1.0f);
    pooled[64 + lane] = (c > 0.f) ? dec_f32(mmax[g * 64 + lane]) : 0.f;
    __syncthreads();
    float acc = bf1[lane];
#pragma unroll
    for (int k = 0; k < 128; ++k) acc += pooled[k] * Wf1[k * 64 + lane];
    acc = fmaxf(acc, 0.f);
    float r = acc * Wf2[lane];
#pragma unroll
    for (int off = 32; off; off >>= 1) r += __shfl_xor(r, off);
    if (lane == 0) out[g] = r + bf2[0];
}

extern "C" void kernel_launch(void* const* d_in, const int* in_sizes, int n_in,
                              void* d_out, int out_size, void* d_ws, size_t ws_size,
                              hipStream_t stream) {
    const float* x    = (const float*)d_in[0];
    const int*   ei   = (const int*)d_in[1];
    const int*   batch= (const int*)d_in[2];
    const float* W1   = (const float*)d_in[3];
    const float* as1  = (const float*)d_in[4];
    const float* ad1  = (const float*)d_in[5];
    const float* b1   = (const float*)d_in[6];
    const float* W2   = (const float*)d_in[7];
    const float* as2  = (const float*)d_in[8];
    const float* ad2  = (const float*)d_in[9];
    const float* b2   = (const float*)d_in[10];
    const float* Wf1  = (const float*)d_in[11];
    const float* bf1  = (const float*)d_in[12];
    const float* Wf2  = (const float*)d_in[13];
    const float* bf2  = (const float*)d_in[14];
    float* out = (float*)d_out;

    const size_t N = N_NODESC;
    float* ws = (float*)d_ws;
    // layout (floats): h16_1 [N*64 words = N*128 bf16] | out1 [N*128 fp32]
    //                  h16_2 [N*32 words = N*64 bf16]  | out2 [N*64 fp32] | small
    ushort_t* h16_1 = (ushort_t*)ws;               // N*128 bf16
    float*    out1  = ws + N * 64;                 // N*128 fp32
    ushort_t* h16_2 = (ushort_t*)(ws + N * 192);   // N*64 bf16
    float*    out2  = ws + N * 224;                // N*64 fp32
    float*    small = ws + N * 288;
    float*    as1b = small;                         // 2N
    float*    ad1b = small + 2 * N;                 // 2N
    float*    as2b = small + 4 * N;                 // N
    float*    ad2b = small + 5 * N;                 // N
    float*    msum = small + 6 * N;                 // 512*64
    unsigned* mmax = (unsigned*)(small + 6 * N + 512 * 64);
    float*    cntb = small + 6 * N + 2 * 512 * 64;  // 512
    int* ip  = (int*)(small + 6 * N + 2 * 512 * 64 + 512);
    int* deg  = ip;              // N
    int* off  = ip + N;          // N
    int* csr  = ip + 2 * N;      // E_TOT
    int* bsum = ip + 2 * N + E_TOTC;  // SCAN_NB

    // init
    hipMemsetAsync(msum, 0, 512 * 64 * 4, stream);
    hipMemsetAsync(cntb, 0, 512 * 4, stream);
    fill_u32<<<(512 * 64 + 255) / 256, 256, 0, stream>>>(mmax, NEG_INF_ENC, 512 * 64);
    fill_u32<<<(N + 255) / 256, 256, 0, stream>>>((unsigned*)deg, 1u, N);  // self-loop

    // CSR build (reused by both layers)
    hist_dst<<<(N_EDGESC + 255) / 256, 256, 0, stream>>>(ei, deg);
    scan_partial<<<SCAN_NB, 256, 0, stream>>>(deg, bsum, N);
    scan_bsum<<<1, SCAN_NB, 0, stream>>>(bsum);
    scan_final<<<SCAN_NB, 256, 0, stream>>>(deg, bsum, off, N);
    scatter_csr<<<(E_TOTC + 255) / 256, 256, 0, stream>>>(ei, off, csr);

    // ---- layer 1 (H=2) ----
    gemm_bf16<128, 8><<<N / 16, dim3(128, 2), 0, stream>>>(x, W1, h16_1, N);
    node_alpha<2><<<(N + 3) / 4, 256, 0, stream>>>(h16_1, as1, ad1, as1b, ad1b, N);
    gat_gather<2, true><<<(N + 3) / 4, 256, 0, stream>>>(off, deg, csr, as1b, ad1b,
                                                         h16_1, b1, out1, N);

    // ---- layer 2 (H=1) ----
    gemm_bf16<64, 8><<<N / 32, dim3(64, 4), 0, stream>>>(out1, W2, h16_2, N);
    node_alpha<1><<<(N + 3) / 4, 256, 0, stream>>>(h16_2, as2, ad2, as2b, ad2b, N);
    gat_gather<1, false><<<(N + 3) / 4, 256, 0, stream>>>(off, deg, csr, as2b, ad2b,
                                                          h16_2, b2, out2, N);

    // ---- pool + MLP ----
    pool_nodes<<<(N + 255) / 256, 256, 0, stream>>>(out2, batch, msum, mmax, cntb, N);
    mlp_head<<<NUM_GRAPHSC, 64, 0, stream>>>(msum, mmax, cntb, Wf1, bf1, Wf2, bf2, out);
}

// Round 6
// 460.116 us; speedup vs baseline: 6.0509x; 1.0217x over previous
//
#include <hip/hip_runtime.h>

#define N_NODESC 100000
#define N_EDGESC 600000
#define E_TOTC   700000
#define NUM_GRAPHSC 512
#define NEG_SLOPE 0.2f
#define NEG_INF_ENC 0x007FFFFFu
#define SCAN_NB 128

typedef unsigned short ushort_t;

// monotone float<->uint mapping so unsigned atomicMax == float max
__device__ __forceinline__ unsigned enc_f32(float f) {
    unsigned u = __float_as_uint(f);
    return (u & 0x80000000u) ? ~u : (u | 0x80000000u);
}
__device__ __forceinline__ float dec_f32(unsigned u) {
    u = (u & 0x80000000u) ? (u ^ 0x80000000u) : ~u;
    return __uint_as_float(u);
}
// exact fp32->bf16 RNE (finite values) and bf16->fp32
__device__ __forceinline__ ushort_t f32_to_bf16(float f) {
    unsigned u = __float_as_uint(f);
    return (ushort_t)((u + 0x7FFFu + ((u >> 16) & 1u)) >> 16);
}
__device__ __forceinline__ float bf16_to_f32(ushort_t h) {
    return __uint_as_float(((unsigned)h) << 16);
}

// fused small-buffer init: msum=0, mmax=-inf, cnt=0 (32768 threads)
__global__ __launch_bounds__(256) void init_small(float* __restrict__ msum,
                                                  unsigned* __restrict__ mmax,
                                                  float* __restrict__ cnt) {
    int i = blockIdx.x * 256 + threadIdx.x;
    msum[i] = 0.f;
    mmax[i] = NEG_INF_ENC;
    if (i < NUM_GRAPHSC) cnt[i] = 0.f;
}

// ---------------- CSR build ----------------
// histogram over ALL edges incl. self-loops (deg pre-zeroed by memset)
__global__ __launch_bounds__(256) void hist_dst(const int* __restrict__ ei,
                                                int* __restrict__ deg) {
    int e = blockIdx.x * blockDim.x + threadIdx.x;
    if (e >= E_TOTC) return;
    int d = (e < N_EDGESC) ? ei[N_EDGESC + e] : e - N_EDGESC;
    atomicAdd(&deg[d], 1);
}

__global__ __launch_bounds__(256) void scan_partial(const int* __restrict__ deg,
                                                    int* __restrict__ bsum, int n) {
    __shared__ int red[256];
    int chunk = (n + SCAN_NB - 1) / SCAN_NB;
    int lo = blockIdx.x * chunk, hi = min(lo + chunk, n);
    int s = 0;
    for (int i = lo + threadIdx.x; i < hi; i += 256) s += deg[i];
    red[threadIdx.x] = s;
    __syncthreads();
    for (int d = 128; d; d >>= 1) {
        if (threadIdx.x < d) red[threadIdx.x] += red[threadIdx.x + d];
        __syncthreads();
    }
    if (threadIdx.x == 0) bsum[blockIdx.x] = red[0];
}

__global__ __launch_bounds__(SCAN_NB) void scan_bsum(int* __restrict__ bsum) {
    __shared__ int tmp[SCAN_NB];
    int t = threadIdx.x;
    tmp[t] = bsum[t];
    __syncthreads();
    for (int d = 1; d < SCAN_NB; d <<= 1) {
        int v = (t >= d) ? tmp[t - d] : 0;
        __syncthreads();
        tmp[t] += v;
        __syncthreads();
    }
    bsum[t] = t ? tmp[t - 1] : 0;
}

__global__ __launch_bounds__(256) void scan_final(const int* __restrict__ deg,
                                                  const int* __restrict__ bsum,
                                                  int* __restrict__ off, int n) {
    __shared__ int tile[256];
    __shared__ int carry;
    int chunk = (n + SCAN_NB - 1) / SCAN_NB;
    int lo = blockIdx.x * chunk, hi = min(lo + chunk, n);
    if (threadIdx.x == 0) carry = bsum[blockIdx.x];
    __syncthreads();
    for (int base = lo; base < hi; base += 256) {
        int i = base + threadIdx.x;
        int v = (i < hi) ? deg[i] : 0;
        tile[threadIdx.x] = v;
        __syncthreads();
        for (int d = 1; d < 256; d <<= 1) {
            int u = (threadIdx.x >= d) ? tile[threadIdx.x - d] : 0;
            __syncthreads();
            tile[threadIdx.x] += u;
            __syncthreads();
        }
        if (i < hi) off[i] = carry + tile[threadIdx.x] - v;
        __syncthreads();
        if (threadIdx.x == 0) carry += tile[255];
        __syncthreads();
    }
}

__global__ __launch_bounds__(256) void scatter_csr(const int* __restrict__ ei,
                                                   int* __restrict__ off,
                                                   int* __restrict__ csr) {
    int e = blockIdx.x * blockDim.x + threadIdx.x;
    if (e >= E_TOTC) return;
    int s, d;
    if (e < N_EDGESC) { s = ei[e]; d = ei[N_EDGESC + e]; } else { s = d = e - N_EDGESC; }
    int slot = atomicAdd(&off[d], 1);
    csr[slot] = s;
}

// ---------------- dense GEMM, bf16 output (R2 register profile; no cross-lane
// epilogue fusion — R3 showed that spills to scratch). ds_read_b128 LDS reads.
// ILV: interleave heads in output layout: elem (h,c) at c*2+h (for H=2 gather)
template <int FOUT, int NPT, bool ILV>
__global__ __launch_bounds__(256) void gemm_bf16(const float* __restrict__ X,
                                                 const float* __restrict__ W,
                                                 ushort_t* __restrict__ Y16, int N) {
    constexpr int K = 128;
    constexpr int NROWS = 256 / FOUT;
    constexpr int NPB = NROWS * NPT;
    __shared__ float xs[NPB][K];
    int tid = threadIdx.y * FOUT + threadIdx.x;
    size_t node0 = (size_t)blockIdx.x * NPB;
    const float4* Xv = (const float4*)(X + node0 * K);
    float4* xsv = (float4*)(&xs[0][0]);
#pragma unroll
    for (int i = 0; i < NPB * K / 4 / 256; ++i) xsv[tid + i * 256] = Xv[tid + i * 256];
    __syncthreads();
    int j = threadIdx.x;
    float acc[NPT];
#pragma unroll
    for (int r = 0; r < NPT; ++r) acc[r] = 0.f;
    const float4* xrow4 = (const float4*)(&xs[threadIdx.y * NPT][0]);
#pragma unroll 8
    for (int k4 = 0; k4 < K / 4; ++k4) {
        float w0 = W[(4 * k4 + 0) * FOUT + j];
        float w1 = W[(4 * k4 + 1) * FOUT + j];
        float w2 = W[(4 * k4 + 2) * FOUT + j];
        float w3 = W[(4 * k4 + 3) * FOUT + j];
#pragma unroll
        for (int r = 0; r < NPT; ++r) {
            float4 xv = xrow4[r * (K / 4) + k4];
            acc[r] += xv.x * w0 + xv.y * w1 + xv.z * w2 + xv.w * w3;
        }
    }
    int idx = ILV ? (((j & 63) << 1) | (j >> 6)) : j;
#pragma unroll
    for (int r = 0; r < NPT; ++r)
        Y16[(node0 + threadIdx.y * NPT + r) * FOUT + idx] = f32_to_bf16(acc[r]);
}

// per-node attention logits from bf16 h: one wave per node.
// H=2 assumes interleaved layout (c*2+h); H=1 plain.
template <int H>
__global__ __launch_bounds__(256) void node_alpha(const ushort_t* __restrict__ H16,
                                                  const float* __restrict__ a_s,
                                                  const float* __restrict__ a_d,
                                                  float* __restrict__ as_out,
                                                  float* __restrict__ ad_out, int N) {
    int wid = threadIdx.x >> 6, lane = threadIdx.x & 63;
    int n = blockIdx.x * 4 + wid;
    if (n >= N) return;
    if (H == 2) {
        const unsigned* hrow = (const unsigned*)(H16 + (size_t)n * 128);
        unsigned u = hrow[lane];
        float h0 = __uint_as_float(u << 16);
        float h1 = __uint_as_float(u & 0xffff0000u);
        float ps0 = h0 * a_s[lane], pd0 = h0 * a_d[lane];
        float ps1 = h1 * a_s[64 + lane], pd1 = h1 * a_d[64 + lane];
#pragma unroll
        for (int off = 32; off; off >>= 1) {
            ps0 += __shfl_xor(ps0, off);
            pd0 += __shfl_xor(pd0, off);
            ps1 += __shfl_xor(ps1, off);
            pd1 += __shfl_xor(pd1, off);
        }
        if (lane == 0) {
            as_out[n * 2 + 0] = ps0; ad_out[n * 2 + 0] = pd0;
            as_out[n * 2 + 1] = ps1; ad_out[n * 2 + 1] = pd1;
        }
    } else {
        float hv = bf16_to_f32(H16[(size_t)n * 64 + lane]);
        float ps = hv * a_s[lane];
        float pd = hv * a_d[lane];
#pragma unroll
        for (int off = 32; off; off >>= 1) {
            ps += __shfl_xor(ps, off);
            pd += __shfl_xor(pd, off);
        }
        if (lane == 0) { as_out[n] = ps; ad_out[n] = pd; }
    }
}

// ---------------- fused gather aggregation, single-pass online softmax ------
// readlane-scalarized edge broadcast: src id + weights live in SGPRs, loads use
// scalar base + loop-invariant lane offset; 4x unroll, weight-0-padded tail.
template <int H, bool RELU>
__global__ __launch_bounds__(256) void gat_gather(const int* __restrict__ off_end,
                                                  const int* __restrict__ deg,
                                                  const int* __restrict__ csr,
                                                  const float* __restrict__ as,
                                                  const float* __restrict__ ad,
                                                  const ushort_t* __restrict__ H16,
                                                  const float* __restrict__ b,
                                                  float* __restrict__ out, int N) {
    constexpr int HC = H * 64;
    int wid = threadIdx.x >> 6, lane = threadIdx.x & 63;
    int n = blockIdx.x * 4 + wid;
    if (n >= N) return;
    int dg = deg[n];
    int o = off_end[n] - dg;
    float adv[H];
#pragma unroll
    for (int h = 0; h < H; ++h) adv[h] = ad[n * H + h];

    float mx[H], acc[H], den[H];
#pragma unroll
    for (int h = 0; h < H; ++h) { mx[h] = -1e30f; acc[h] = 0.f; den[h] = 0.f; }

    const unsigned* Hu = (const unsigned*)H16;  // H==2 interleaved rows (64 u32)

    for (int base = 0; base < dg; base += 64) {
        int i = base + lane;
        bool valid = i < dg;
        int s = valid ? csr[o + i] : 0;
        float v[H];
        if (H == 2) {
            float2 p = valid ? ((const float2*)as)[s] : make_float2(-1e30f, -1e30f);
            v[0] = p.x + adv[0];
            v[H - 1] = p.y + adv[H - 1];
        } else {
            v[0] = valid ? as[s] + adv[0] : -1e30f;
        }
#pragma unroll
        for (int h = 0; h < H; ++h) {
            if (valid) v[h] = v[h] >= 0.f ? v[h] : NEG_SLOPE * v[h];
            float cm = v[h];
#pragma unroll
            for (int sh = 32; sh; sh >>= 1) cm = fmaxf(cm, __shfl_xor(cm, sh));
            float nm = fmaxf(mx[h], cm);
            float scale = __expf(mx[h] - nm);
            den[h] *= scale;
            acc[h] *= scale;
            mx[h] = nm;
            v[h] = valid ? __expf(v[h] - nm) : 0.f;  // weight; 0 for invalid lanes
            den[h] += v[h];
        }
        int cnt = min(dg - base, 64);
        int cnt4 = (cnt + 3) & ~3;  // pad: lanes >= cnt have weight 0, s = 0
        for (int j = 0; j < cnt4; j += 4) {
#pragma unroll
            for (int u = 0; u < 4; ++u) {
                int jj = j + u;
                int sj = __builtin_amdgcn_readlane(s, jj);
                float w0 = __uint_as_float(
                    __builtin_amdgcn_readlane(__float_as_uint(v[0]), jj));
                if (H == 2) {
                    float w1 = __uint_as_float(
                        __builtin_amdgcn_readlane(__float_as_uint(v[H - 1]), jj));
                    unsigned hu = Hu[(size_t)sj * 64 + lane];
                    acc[0] += w0 * __uint_as_float(hu << 16);
                    acc[H - 1] += w1 * __uint_as_float(hu & 0xffff0000u);
                } else {
                    acc[0] += w0 * bf16_to_f32(H16[(size_t)sj * 64 + lane]);
                }
            }
        }
    }
#pragma unroll
    for (int h = 0; h < H; ++h) {
#pragma unroll
        for (int sh = 32; sh; sh >>= 1) den[h] += __shfl_xor(den[h], sh);
        float v = acc[h] / fmaxf(den[h], 1e-16f) + b[h * 64 + lane];
        if (RELU) v = fmaxf(v, 0.f);
        out[(size_t)n * HC + h * 64 + lane] = v;
    }
}

// ---------------- pooling: batch is SORTED -> segment-local reduce ----------
__global__ __launch_bounds__(256) void pool_nodes(const float* __restrict__ h2,
                                                  const int* __restrict__ batch,
                                                  float* __restrict__ msum,
                                                  unsigned* __restrict__ mmax,
                                                  float* __restrict__ cnt, int N) {
    int wid = threadIdx.x >> 6, lane = threadIdx.x & 63;
    int n0 = (blockIdx.x * 4 + wid) * 64;
    if (n0 >= N) return;
    int n1 = min(n0 + 64, N);
    int curg = batch[n0];
    float s = 0.f, m = -1e30f;
    int c = 0;
    for (int n = n0; n < n1; ++n) {
        int g = batch[n];
        float v = h2[(size_t)n * 64 + lane];
        if (g != curg) {
            atomicAdd(&msum[curg * 64 + lane], s);
            atomicMax(&mmax[curg * 64 + lane], enc_f32(m));
            if (lane == 0) atomicAdd(&cnt[curg], (float)c);
            s = 0.f; m = -1e30f; c = 0; curg = g;
        }
        s += v;
        m = fmaxf(m, v);
        ++c;
    }
    atomicAdd(&msum[curg * 64 + lane], s);
    atomicMax(&mmax[curg * 64 + lane], enc_f32(m));
    if (lane == 0) atomicAdd(&cnt[curg], (float)c);
}

__global__ __launch_bounds__(64) void mlp_head(const float* __restrict__ msum,
                                               const unsigned* __restrict__ mmax,
                                               const float* __restrict__ cnt,
                                               const float* __restrict__ Wf1,
                                               const float* __restrict__ bf1,
                                               const float* __restrict__ Wf2,
                                               const float* __restrict__ bf2,
                                               float* __restrict__ out) {
    __shared__ float pooled[128];
    int g = blockIdx.x, lane = threadIdx.x;
    float c = cnt[g];
    pooled[lane] = msum[g * 64 + lane] / fmaxf(c, 1.0f);
    pooled[64 + lane] = (c > 0.f) ? dec_f32(mmax[g * 64 + lane]) : 0.f;
    __syncthreads();
    float acc = bf1[lane];
#pragma unroll
    for (int k = 0; k < 128; ++k) acc += pooled[k] * Wf1[k * 64 + lane];
    acc = fmaxf(acc, 0.f);
    float r = acc * Wf2[lane];
#pragma unroll
    for (int off = 32; off; off >>= 1) r += __shfl_xor(r, off);
    if (lane == 0) out[g] = r + bf2[0];
}

extern "C" void kernel_launch(void* const* d_in, const int* in_sizes, int n_in,
                              void* d_out, int out_size, void* d_ws, size_t ws_size,
                              hipStream_t stream) {
    const float* x    = (const float*)d_in[0];
    const int*   ei   = (const int*)d_in[1];
    const int*   batch= (const int*)d_in[2];
    const float* W1   = (const float*)d_in[3];
    const float* as1  = (const float*)d_in[4];
    const float* ad1  = (const float*)d_in[5];
    const float* b1   = (const float*)d_in[6];
    const float* W2   = (const float*)d_in[7];
    const float* as2  = (const float*)d_in[8];
    const float* ad2  = (const float*)d_in[9];
    const float* b2   = (const float*)d_in[10];
    const float* Wf1  = (const float*)d_in[11];
    const float* bf1  = (const float*)d_in[12];
    const float* Wf2  = (const float*)d_in[13];
    const float* bf2  = (const float*)d_in[14];
    float* out = (float*)d_out;

    const size_t N = N_NODESC;
    float* ws = (float*)d_ws;
    ushort_t* h16_1 = (ushort_t*)ws;               // N*128 bf16 (interleaved heads)
    float*    out1  = ws + N * 64;                 // N*128 fp32
    ushort_t* h16_2 = (ushort_t*)(ws + N * 192);   // N*64 bf16
    float*    out2  = ws + N * 224;                // N*64 fp32
    float*    small = ws + N * 288;
    float*    as1b = small;                         // 2N
    float*    ad1b = small + 2 * N;                 // 2N
    float*    as2b = small + 4 * N;                 // N
    float*    ad2b = small + 5 * N;                 // N
    float*    msum = small + 6 * N;                 // 512*64
    unsigned* mmax = (unsigned*)(small + 6 * N + 512 * 64);
    float*    cntb = small + 6 * N + 2 * 512 * 64;  // 512
    int* ip  = (int*)(small + 6 * N + 2 * 512 * 64 + 512);
    int* deg  = ip;              // N
    int* off  = ip + N;          // N
    int* csr  = ip + 2 * N;      // E_TOT
    int* bsum = ip + 2 * N + E_TOTC;  // SCAN_NB

    // init
    init_small<<<(NUM_GRAPHSC * 64) / 256, 256, 0, stream>>>(msum, mmax, cntb);
    hipMemsetAsync(deg, 0, N * 4, stream);

    // CSR build (reused by both layers); hist includes self-loops
    hist_dst<<<(E_TOTC + 255) / 256, 256, 0, stream>>>(ei, deg);
    scan_partial<<<SCAN_NB, 256, 0, stream>>>(deg, bsum, N);
    scan_bsum<<<1, SCAN_NB, 0, stream>>>(bsum);
    scan_final<<<SCAN_NB, 256, 0, stream>>>(deg, bsum, off, N);
    scatter_csr<<<(E_TOTC + 255) / 256, 256, 0, stream>>>(ei, off, csr);

    // ---- layer 1 (H=2, interleaved h16 layout) ----
    gemm_bf16<128, 8, true><<<N / 16, dim3(128, 2), 0, stream>>>(x, W1, h16_1, N);
    node_alpha<2><<<(N + 3) / 4, 256, 0, stream>>>(h16_1, as1, ad1, as1b, ad1b, N);
    gat_gather<2, true><<<(N + 3) / 4, 256, 0, stream>>>(off, deg, csr, as1b, ad1b,
                                                         h16_1, b1, out1, N);

    // ---- layer 2 (H=1) ----
    gemm_bf16<64, 8, false><<<N / 32, dim3(64, 4), 0, stream>>>(out1, W2, h16_2, N);
    node_alpha<1><<<(N + 3) / 4, 256, 0, stream>>>(h16_2, as2, ad2, as2b, ad2b, N);
    gat_gather<1, false><<<(N + 3) / 4, 256, 0, stream>>>(off, deg, csr, as2b, ad2b,
                                                          h16_2, b2, out2, N);

    // ---- pool + MLP ----
    pool_nodes<<<(N + 255) / 256, 256, 0, stream>>>(out2, batch, msum, mmax, cntb, N);
    mlp_head<<<NUM_GRAPHSC, 64, 0, stream>>>(msum, mmax, cntb, Wf1, bf1, Wf2, bf2, out);
}

// Round 7
// 434.832 us; speedup vs baseline: 6.4028x; 1.0581x over previous
//
#include <hip/hip_runtime.h>

#define N_NODESC 100000
#define N_EDGESC 600000
#define E_TOTC   700000
#define NUM_GRAPHSC 512
#define NEG_SLOPE 0.2f
#define NEG_INF_ENC 0x007FFFFFu
#define SCAN_NB 128

typedef unsigned short ushort_t;

// monotone float<->uint mapping so unsigned atomicMax == float max
__device__ __forceinline__ unsigned enc_f32(float f) {
    unsigned u = __float_as_uint(f);
    return (u & 0x80000000u) ? ~u : (u | 0x80000000u);
}
__device__ __forceinline__ float dec_f32(unsigned u) {
    u = (u & 0x80000000u) ? (u ^ 0x80000000u) : ~u;
    return __uint_as_float(u);
}
// exact fp32->bf16 RNE (finite values) and bf16->fp32
__device__ __forceinline__ ushort_t f32_to_bf16(float f) {
    unsigned u = __float_as_uint(f);
    return (ushort_t)((u + 0x7FFFu + ((u >> 16) & 1u)) >> 16);
}
__device__ __forceinline__ float bf16_to_f32(ushort_t h) {
    return __uint_as_float(((unsigned)h) << 16);
}
__device__ __forceinline__ unsigned pack_bf16x2(float a, float b) {
    return (unsigned)f32_to_bf16(a) | ((unsigned)f32_to_bf16(b) << 16);
}

// fused small-buffer init: msum=0, mmax=-inf, cnt=0 (32768 threads)
__global__ __launch_bounds__(256) void init_small(float* __restrict__ msum,
                                                  unsigned* __restrict__ mmax,
                                                  float* __restrict__ cnt) {
    int i = blockIdx.x * 256 + threadIdx.x;
    msum[i] = 0.f;
    mmax[i] = NEG_INF_ENC;
    if (i < NUM_GRAPHSC) cnt[i] = 0.f;
}

// ---------------- CSR build ----------------
__global__ __launch_bounds__(256) void hist_dst(const int* __restrict__ ei,
                                                int* __restrict__ deg) {
    int e = blockIdx.x * blockDim.x + threadIdx.x;
    if (e >= E_TOTC) return;
    int d = (e < N_EDGESC) ? ei[N_EDGESC + e] : e - N_EDGESC;
    atomicAdd(&deg[d], 1);
}

__global__ __launch_bounds__(256) void scan_partial(const int* __restrict__ deg,
                                                    int* __restrict__ bsum, int n) {
    __shared__ int red[256];
    int chunk = (n + SCAN_NB - 1) / SCAN_NB;
    int lo = blockIdx.x * chunk, hi = min(lo + chunk, n);
    int s = 0;
    for (int i = lo + threadIdx.x; i < hi; i += 256) s += deg[i];
    red[threadIdx.x] = s;
    __syncthreads();
    for (int d = 128; d; d >>= 1) {
        if (threadIdx.x < d) red[threadIdx.x] += red[threadIdx.x + d];
        __syncthreads();
    }
    if (threadIdx.x == 0) bsum[blockIdx.x] = red[0];
}

__global__ __launch_bounds__(SCAN_NB) void scan_bsum(int* __restrict__ bsum) {
    __shared__ int tmp[SCAN_NB];
    int t = threadIdx.x;
    tmp[t] = bsum[t];
    __syncthreads();
    for (int d = 1; d < SCAN_NB; d <<= 1) {
        int v = (t >= d) ? tmp[t - d] : 0;
        __syncthreads();
        tmp[t] += v;
        __syncthreads();
    }
    bsum[t] = t ? tmp[t - 1] : 0;
}

__global__ __launch_bounds__(256) void scan_final(const int* __restrict__ deg,
                                                  const int* __restrict__ bsum,
                                                  int* __restrict__ off, int n) {
    __shared__ int tile[256];
    __shared__ int carry;
    int chunk = (n + SCAN_NB - 1) / SCAN_NB;
    int lo = blockIdx.x * chunk, hi = min(lo + chunk, n);
    if (threadIdx.x == 0) carry = bsum[blockIdx.x];
    __syncthreads();
    for (int base = lo; base < hi; base += 256) {
        int i = base + threadIdx.x;
        int v = (i < hi) ? deg[i] : 0;
        tile[threadIdx.x] = v;
        __syncthreads();
        for (int d = 1; d < 256; d <<= 1) {
            int u = (threadIdx.x >= d) ? tile[threadIdx.x - d] : 0;
            __syncthreads();
            tile[threadIdx.x] += u;
            __syncthreads();
        }
        if (i < hi) off[i] = carry + tile[threadIdx.x] - v;
        __syncthreads();
        if (threadIdx.x == 0) carry += tile[255];
        __syncthreads();
    }
}

__global__ __launch_bounds__(256) void scatter_csr(const int* __restrict__ ei,
                                                   int* __restrict__ off,
                                                   int* __restrict__ csr) {
    int e = blockIdx.x * blockDim.x + threadIdx.x;
    if (e >= E_TOTC) return;
    int s, d;
    if (e < N_EDGESC) { s = ei[e]; d = ei[N_EDGESC + e]; } else { s = d = e - N_EDGESC; }
    int slot = atomicAdd(&off[d], 1);
    csr[slot] = s;
}

// ---------------- register-tiled GEMM, bf16 output ----------------
// C-tile 128 x FOUT per block; micro-tile 8m x (FOUT/16)n per thread.
// K=128 staged in two 64-deep LDS stages: xsT[k][m] (transposed, +4 pad),
// ws[k][n]. 1 B LDS read per FMA (vs 4 B in the old broadcast kernel).
// PERM (layer 1): W columns permuted j=h*64+c -> c*2+h so the bf16 output is
// written directly in the head-interleaved layout the gather consumes.
// Keep micro-tile <= 8x8: acc=64 VGPR; R3 lesson: no cross-lane epilogues here.
template <int FOUT, bool PERM>
__global__ __launch_bounds__(256) void gemm_tiled(const float* __restrict__ X,
                                                  const float* __restrict__ W,
                                                  ushort_t* __restrict__ Y16, int N) {
    constexpr int MT = 128;
    constexpr int NM = FOUT / 16;   // 8 (L1) / 4 (L2) outputs per thread in n
    constexpr int KS = 64;
    constexpr int XP = 132;         // xsT row stride (pad 4: staging 2-way banks)
    __shared__ float xsT[KS][XP];   // 33.8 KB
    __shared__ float ws[KS][FOUT];  // 32 KB (L1) / 16 KB (L2)
    int tid = threadIdx.x;
    int tx = tid & 15, ty = tid >> 4;
    int m0 = ty * 8, n0 = tx * NM;
    size_t node0 = (size_t)blockIdx.x * MT;

    float acc[8][NM];
#pragma unroll
    for (int i = 0; i < 8; ++i)
#pragma unroll
        for (int j = 0; j < NM; ++j) acc[i][j] = 0.f;

    for (int ks = 0; ks < 128; ks += KS) {
        __syncthreads();
        // stage X tile transposed: 128 m x 64 k; thread loads 8 float4 along k
#pragma unroll
        for (int it = 0; it < 8; ++it) {
            int idx = it * 256 + tid;
            int k4 = idx & 15;
            int m = idx >> 4;
            size_t mrow = node0 + m;
            if (mrow >= N) mrow = N - 1;  // clamp: rows >=N never stored
            float4 xv = *(const float4*)(X + mrow * 128 + ks + k4 * 4);
            xsT[k4 * 4 + 0][m] = xv.x;
            xsT[k4 * 4 + 1][m] = xv.y;
            xsT[k4 * 4 + 2][m] = xv.z;
            xsT[k4 * 4 + 3][m] = xv.w;
        }
        // stage W tile: 64 k x FOUT
#pragma unroll
        for (int it = 0; it < FOUT / 16; ++it) {
            int idx = it * 256 + tid;
            int j4 = idx & (FOUT / 4 - 1);
            int k = idx / (FOUT / 4);
            float4 wv = *(const float4*)(W + (size_t)(ks + k) * FOUT + j4 * 4);
            if (PERM) {
                float c[4] = {wv.x, wv.y, wv.z, wv.w};
#pragma unroll
                for (int jj = 0; jj < 4; ++jj) {
                    int j = j4 * 4 + jj;
                    ws[k][((j & 63) << 1) | (j >> 6)] = c[jj];
                }
            } else {
                *(float4*)&ws[k][j4 * 4] = wv;
            }
        }
        __syncthreads();
#pragma unroll 8
        for (int kk = 0; kk < KS; ++kk) {
            float a[8], b[NM];
            *(float4*)&a[0] = *(const float4*)&xsT[kk][m0];
            *(float4*)&a[4] = *(const float4*)&xsT[kk][m0 + 4];
#pragma unroll
            for (int q = 0; q < NM / 4; ++q)
                *(float4*)&b[q * 4] = *(const float4*)&ws[kk][n0 + q * 4];
#pragma unroll
            for (int i = 0; i < 8; ++i)
#pragma unroll
                for (int j = 0; j < NM; ++j) acc[i][j] += a[i] * b[j];
        }
    }
    // epilogue: pack bf16, one vector store per row (n-range is contiguous)
#pragma unroll
    for (int i = 0; i < 8; ++i) {
        size_t mrow = node0 + m0 + i;
        if (mrow >= N) break;
        unsigned p[NM / 2];
#pragma unroll
        for (int q = 0; q < NM / 2; ++q)
            p[q] = pack_bf16x2(acc[i][2 * q], acc[i][2 * q + 1]);
        ushort_t* dst = Y16 + mrow * FOUT + n0;
        if (NM == 8)
            *(uint4*)dst = make_uint4(p[0], p[1], p[2], p[3]);
        else
            *(uint2*)dst = make_uint2(p[0], p[1]);
    }
}

// per-node attention logits from bf16 h: one wave per node.
// H=2 assumes interleaved layout (c*2+h); H=1 plain.
template <int H>
__global__ __launch_bounds__(256) void node_alpha(const ushort_t* __restrict__ H16,
                                                  const float* __restrict__ a_s,
                                                  const float* __restrict__ a_d,
                                                  float* __restrict__ as_out,
                                                  float* __restrict__ ad_out, int N) {
    int wid = threadIdx.x >> 6, lane = threadIdx.x & 63;
    int n = blockIdx.x * 4 + wid;
    if (n >= N) return;
    if (H == 2) {
        const unsigned* hrow = (const unsigned*)(H16 + (size_t)n * 128);
        unsigned u = hrow[lane];
        float h0 = __uint_as_float(u << 16);
        float h1 = __uint_as_float(u & 0xffff0000u);
        float ps0 = h0 * a_s[lane], pd0 = h0 * a_d[lane];
        float ps1 = h1 * a_s[64 + lane], pd1 = h1 * a_d[64 + lane];
#pragma unroll
        for (int off = 32; off; off >>= 1) {
            ps0 += __shfl_xor(ps0, off);
            pd0 += __shfl_xor(pd0, off);
            ps1 += __shfl_xor(ps1, off);
            pd1 += __shfl_xor(pd1, off);
        }
        if (lane == 0) {
            as_out[n * 2 + 0] = ps0; ad_out[n * 2 + 0] = pd0;
            as_out[n * 2 + 1] = ps1; ad_out[n * 2 + 1] = pd1;
        }
    } else {
        float hv = bf16_to_f32(H16[(size_t)n * 64 + lane]);
        float ps = hv * a_s[lane];
        float pd = hv * a_d[lane];
#pragma unroll
        for (int off = 32; off; off >>= 1) {
            ps += __shfl_xor(ps, off);
            pd += __shfl_xor(pd, off);
        }
        if (lane == 0) { as_out[n] = ps; ad_out[n] = pd; }
    }
}

// ---------------- fused gather aggregation, single-pass online softmax ------
// readlane-scalarized edge broadcast (R6 win): src id + weights in SGPRs.
template <int H, bool RELU>
__global__ __launch_bounds__(256) void gat_gather(const int* __restrict__ off_end,
                                                  const int* __restrict__ deg,
                                                  const int* __restrict__ csr,
                                                  const float* __restrict__ as,
                                                  const float* __restrict__ ad,
                                                  const ushort_t* __restrict__ H16,
                                                  const float* __restrict__ b,
                                                  float* __restrict__ out, int N) {
    constexpr int HC = H * 64;
    int wid = threadIdx.x >> 6, lane = threadIdx.x & 63;
    int n = blockIdx.x * 4 + wid;
    if (n >= N) return;
    int dg = deg[n];
    int o = off_end[n] - dg;
    float adv[H];
#pragma unroll
    for (int h = 0; h < H; ++h) adv[h] = ad[n * H + h];

    float mx[H], acc[H], den[H];
#pragma unroll
    for (int h = 0; h < H; ++h) { mx[h] = -1e30f; acc[h] = 0.f; den[h] = 0.f; }

    const unsigned* Hu = (const unsigned*)H16;  // H==2 interleaved rows (64 u32)

    for (int base = 0; base < dg; base += 64) {
        int i = base + lane;
        bool valid = i < dg;
        int s = valid ? csr[o + i] : 0;
        float v[H];
        if (H == 2) {
            float2 p = valid ? ((const float2*)as)[s] : make_float2(-1e30f, -1e30f);
            v[0] = p.x + adv[0];
            v[H - 1] = p.y + adv[H - 1];
        } else {
            v[0] = valid ? as[s] + adv[0] : -1e30f;
        }
#pragma unroll
        for (int h = 0; h < H; ++h) {
            if (valid) v[h] = v[h] >= 0.f ? v[h] : NEG_SLOPE * v[h];
            float cm = v[h];
#pragma unroll
            for (int sh = 32; sh; sh >>= 1) cm = fmaxf(cm, __shfl_xor(cm, sh));
            float nm = fmaxf(mx[h], cm);
            float scale = __expf(mx[h] - nm);
            den[h] *= scale;
            acc[h] *= scale;
            mx[h] = nm;
            v[h] = valid ? __expf(v[h] - nm) : 0.f;  // weight; 0 for invalid lanes
            den[h] += v[h];
        }
        int cnt = min(dg - base, 64);
        int cnt4 = (cnt + 3) & ~3;  // pad: lanes >= cnt have weight 0, s = 0
        for (int j = 0; j < cnt4; j += 4) {
#pragma unroll
            for (int u = 0; u < 4; ++u) {
                int jj = j + u;
                int sj = __builtin_amdgcn_readlane(s, jj);
                float w0 = __uint_as_float(
                    __builtin_amdgcn_readlane(__float_as_uint(v[0]), jj));
                if (H == 2) {
                    float w1 = __uint_as_float(
                        __builtin_amdgcn_readlane(__float_as_uint(v[H - 1]), jj));
                    unsigned hu = Hu[(size_t)sj * 64 + lane];
                    acc[0] += w0 * __uint_as_float(hu << 16);
                    acc[H - 1] += w1 * __uint_as_float(hu & 0xffff0000u);
                } else {
                    acc[0] += w0 * bf16_to_f32(H16[(size_t)sj * 64 + lane]);
                }
            }
        }
    }
#pragma unroll
    for (int h = 0; h < H; ++h) {
#pragma unroll
        for (int sh = 32; sh; sh >>= 1) den[h] += __shfl_xor(den[h], sh);
        float v = acc[h] / fmaxf(den[h], 1e-16f) + b[h * 64 + lane];
        if (RELU) v = fmaxf(v, 0.f);
        out[(size_t)n * HC + h * 64 + lane] = v;
    }
}

// ---------------- pooling: batch is SORTED -> segment-local reduce ----------
__global__ __launch_bounds__(256) void pool_nodes(const float* __restrict__ h2,
                                                  const int* __restrict__ batch,
                                                  float* __restrict__ msum,
                                                  unsigned* __restrict__ mmax,
                                                  float* __restrict__ cnt, int N) {
    int wid = threadIdx.x >> 6, lane = threadIdx.x & 63;
    int n0 = (blockIdx.x * 4 + wid) * 64;
    if (n0 >= N) return;
    int n1 = min(n0 + 64, N);
    int curg = batch[n0];
    float s = 0.f, m = -1e30f;
    int c = 0;
    for (int n = n0; n < n1; ++n) {
        int g = batch[n];
        float v = h2[(size_t)n * 64 + lane];
        if (g != curg) {
            atomicAdd(&msum[curg * 64 + lane], s);
            atomicMax(&mmax[curg * 64 + lane], enc_f32(m));
            if (lane == 0) atomicAdd(&cnt[curg], (float)c);
            s = 0.f; m = -1e30f; c = 0; curg = g;
        }
        s += v;
        m = fmaxf(m, v);
        ++c;
    }
    atomicAdd(&msum[curg * 64 + lane], s);
    atomicMax(&mmax[curg * 64 + lane], enc_f32(m));
    if (lane == 0) atomicAdd(&cnt[curg], (float)c);
}

__global__ __launch_bounds__(64) void mlp_head(const float* __restrict__ msum,
                                               const unsigned* __restrict__ mmax,
                                               const float* __restrict__ cnt,
                                               const float* __restrict__ Wf1,
                                               const float* __restrict__ bf1,
                                               const float* __restrict__ Wf2,
                                               const float* __restrict__ bf2,
                                               float* __restrict__ out) {
    __shared__ float pooled[128];
    int g = blockIdx.x, lane = threadIdx.x;
    float c = cnt[g];
    pooled[lane] = msum[g * 64 + lane] / fmaxf(c, 1.0f);
    pooled[64 + lane] = (c > 0.f) ? dec_f32(mmax[g * 64 + lane]) : 0.f;
    __syncthreads();
    float acc = bf1[lane];
#pragma unroll
    for (int k = 0; k < 128; ++k) acc += pooled[k] * Wf1[k * 64 + lane];
    acc = fmaxf(acc, 0.f);
    float r = acc * Wf2[lane];
#pragma unroll
    for (int off = 32; off; off >>= 1) r += __shfl_xor(r, off);
    if (lane == 0) out[g] = r + bf2[0];
}

extern "C" void kernel_launch(void* const* d_in, const int* in_sizes, int n_in,
                              void* d_out, int out_size, void* d_ws, size_t ws_size,
                              hipStream_t stream) {
    const float* x    = (const float*)d_in[0];
    const int*   ei   = (const int*)d_in[1];
    const int*   batch= (const int*)d_in[2];
    const float* W1   = (const float*)d_in[3];
    const float* as1  = (const float*)d_in[4];
    const float* ad1  = (const float*)d_in[5];
    const float* b1   = (const float*)d_in[6];
    const float* W2   = (const float*)d_in[7];
    const float* as2  = (const float*)d_in[8];
    const float* ad2  = (const float*)d_in[9];
    const float* b2   = (const float*)d_in[10];
    const float* Wf1  = (const float*)d_in[11];
    const float* bf1  = (const float*)d_in[12];
    const float* Wf2  = (const float*)d_in[13];
    const float* bf2  = (const float*)d_in[14];
    float* out = (float*)d_out;

    const size_t N = N_NODESC;
    float* ws = (float*)d_ws;
    ushort_t* h16_1 = (ushort_t*)ws;               // N*128 bf16 (interleaved heads)
    float*    out1  = ws + N * 64;                 // N*128 fp32
    ushort_t* h16_2 = (ushort_t*)(ws + N * 192);   // N*64 bf16
    float*    out2  = ws + N * 224;                // N*64 fp32
    float*    small = ws + N * 288;
    float*    as1b = small;                         // 2N
    float*    ad1b = small + 2 * N;                 // 2N
    float*    as2b = small + 4 * N;                 // N
    float*    ad2b = small + 5 * N;                 // N
    float*    msum = small + 6 * N;                 // 512*64
    unsigned* mmax = (unsigned*)(small + 6 * N + 512 * 64);
    float*    cntb = small + 6 * N + 2 * 512 * 64;  // 512
    int* ip  = (int*)(small + 6 * N + 2 * 512 * 64 + 512);
    int* deg  = ip;              // N
    int* off  = ip + N;          // N
    int* csr  = ip + 2 * N;      // E_TOT
    int* bsum = ip + 2 * N + E_TOTC;  // SCAN_NB

    // init
    init_small<<<(NUM_GRAPHSC * 64) / 256, 256, 0, stream>>>(msum, mmax, cntb);
    hipMemsetAsync(deg, 0, N * 4, stream);

    // CSR build (reused by both layers); hist includes self-loops
    hist_dst<<<(E_TOTC + 255) / 256, 256, 0, stream>>>(ei, deg);
    scan_partial<<<SCAN_NB, 256, 0, stream>>>(deg, bsum, N);
    scan_bsum<<<1, SCAN_NB, 0, stream>>>(bsum);
    scan_final<<<SCAN_NB, 256, 0, stream>>>(deg, bsum, off, N);
    scatter_csr<<<(E_TOTC + 255) / 256, 256, 0, stream>>>(ei, off, csr);

    const int NBLK = (N_NODESC + 127) / 128;  // 782

    // ---- layer 1 (H=2, head-interleaved h16 layout via PERM) ----
    gemm_tiled<128, true><<<NBLK, 256, 0, stream>>>(x, W1, h16_1, N);
    node_alpha<2><<<(N + 3) / 4, 256, 0, stream>>>(h16_1, as1, ad1, as1b, ad1b, N);
    gat_gather<2, true><<<(N + 3) / 4, 256, 0, stream>>>(off, deg, csr, as1b, ad1b,
                                                         h16_1, b1, out1, N);

    // ---- layer 2 (H=1) ----
    gemm_tiled<64, false><<<NBLK, 256, 0, stream>>>(out1, W2, h16_2, N);
    node_alpha<1><<<(N + 3) / 4, 256, 0, stream>>>(h16_2, as2, ad2, as2b, ad2b, N);
    gat_gather<1, false><<<(N + 3) / 4, 256, 0, stream>>>(off, deg, csr, as2b, ad2b,
                                                          h16_2, b2, out2, N);

    // ---- pool + MLP ----
    pool_nodes<<<(N + 255) / 256, 256, 0, stream>>>(out2, batch, msum, mmax, cntb, N);
    mlp_head<<<NUM_GRAPHSC, 64, 0, stream>>>(msum, mmax, cntb, Wf1, bf1, Wf2, bf2, out);
}